// Round 4
// baseline (521.783 us; speedup 1.0000x reference)
//
#include <hip/hip_runtime.h>
#include <hip/hip_bf16.h>

typedef __attribute__((ext_vector_type(8))) short short8;
typedef __attribute__((ext_vector_type(4))) float f32x4;
typedef unsigned short ushort_t;

// ---------------- problem constants ----------------
static constexpr int Bn  = 8192;
static constexpr int SEQ = 1024;
static constexpr int EMB = 768;
static constexpr int LAT = 256;

// output offsets (floats): (z, Lp, Lo, Lf, Lg, Ls, Rp, Ro, Rf, Rg, Rs, glob, emb)
static constexpr size_t OFF_Z   = 0;
static constexpr size_t OFF_LP  = 2097152;
static constexpr size_t OFF_LO  = 2424832;
static constexpr size_t OFF_LF  = 4063232;
static constexpr size_t OFF_LG  = 10616832;
static constexpr size_t OFF_LS  = 35192832;
static constexpr size_t OFF_RP  = 133496832;  // Rp..Rs,glob contiguous, stride 8192*768
static constexpr size_t OFF_EMB = 171245568;

// Logit region [OFF_LO, OFF_RP) = 131072000 floats is sentinel-filled LATE in the
// pipeline -> use its head as scratch for the pre-split bf16 operands (~72 MB).
// Float offsets relative to out:
static constexpr size_t SCR      = OFF_LO;
static constexpr size_t S_SEQ_H  = SCR + 0;         // 8192x1024 bf16 = 4194304 fl
static constexpr size_t S_SEQ_L  = SCR + 4194304;
static constexpr size_t S_EMB_H  = SCR + 8388608;   // 8192x768  = 3145728 fl
static constexpr size_t S_EMB_L  = SCR + 11534336;
static constexpr size_t S_Z_H    = SCR + 14680064;  // 8192x256  = 1048576 fl
static constexpr size_t S_Z_L    = SCR + 15728640;
static constexpr size_t S_REC_H  = SCR + 16777216;  // 4608x256  = 589824 fl
static constexpr size_t S_REC_L  = SCR + 17367040;  // end 17956864 << 131072000

// d_ws layout (ushort units). R2/R3 used 8.65MB of ws successfully -> ws_size >= 8.65MB.
static constexpr size_t WS_DNA_H = 0;        // [768][1024]
static constexpr size_t WS_DNA_L = 786432;
static constexpr size_t WS_ENC_H = 1572864;  // [256][768]
static constexpr size_t WS_ENC_L = 1769472;
static constexpr size_t WS_COMPACT_FL = 983040; // float offset: 4 lvl x 8192 x 6 fl (786KB)
// total ws use: 3.93MB + 0.79MB = 4.72MB  (< 8.65MB proven)

#define MASKED_VAL (-1.0e30f)
static constexpr size_t FILL_N = OFF_RP - OFF_LO;   // 131072000 floats

// ---------------- bf16 split helpers (RNE) ----------------
__device__ __forceinline__ ushort_t bfbits(float f) {
    return __builtin_bit_cast(ushort_t, __float2bfloat16(f));
}
__device__ __forceinline__ float bf2f(ushort_t h) {
    return __builtin_bit_cast(float, ((unsigned)h) << 16);
}
__device__ __forceinline__ void split2(float f, ushort_t& h, ushort_t& l) {
    h = bfbits(f);
    l = bfbits(f - bf2f(h));
}

// ---------------- prep: split f32 [M][K] -> hi/lo bf16 [M][K] (linear) --------
__global__ __launch_bounds__(256)
void split_f32(const float* __restrict__ src, ushort_t* __restrict__ h,
               ushort_t* __restrict__ l, int n8)
{
    const int i = blockIdx.x * 256 + threadIdx.x;
    if (i >= n8) return;
    const float4 a = ((const float4*)src)[(size_t)i * 2];
    const float4 b = ((const float4*)src)[(size_t)i * 2 + 1];
    const float f[8] = {a.x, a.y, a.z, a.w, b.x, b.y, b.z, b.w};
    short8 hh, ll;
    #pragma unroll
    for (int j = 0; j < 8; ++j) {
        ushort_t hv, lv;
        split2(f[j], hv, lv);
        hh[j] = (short)hv; ll[j] = (short)lv;
    }
    ((short8*)h)[i] = hh;
    ((short8*)l)[i] = ll;
}

// ---------------- prep: [K][N] f32 -> hi/lo bf16 [N][K] (transpose+split) -----
template <int K, int N>
__global__ void prep_wt(const float* __restrict__ src, ushort_t* __restrict__ dh,
                        ushort_t* __restrict__ dl) {
    for (int idx = blockIdx.x * 256 + threadIdx.x; idx < K * N; idx += gridDim.x * 256) {
        int k = idx / N, n = idx - k * N;
        ushort_t h, l;
        split2(src[idx], h, l);
        dh[(size_t)n * K + k] = h;
        dl[(size_t)n * K + k] = l;
    }
}

struct Ptr6 { const float* p[6]; };
__global__ void prep_rec(Ptr6 s, ushort_t* __restrict__ dh, ushort_t* __restrict__ dl) {
    constexpr int PER = 256 * 768;
    for (int idx = blockIdx.x * 256 + threadIdx.x; idx < 6 * PER; idx += gridDim.x * 256) {
        int m = idx / PER, r = idx - m * PER;
        int k = r / 768, n = r - k * 768;
        ushort_t h, l;
        split2(s.p[m][r], h, l);
        size_t d = (size_t)(m * 768 + n) * 256 + k;
        dh[d] = h;
        dl[d] = l;
    }
}

// ---------------- bf16x3 emulated-fp32 GEMM (pre-split operands) ----------------
// C[M,N] = A[M,K] @ B[K,N]; Ahg/Alg bf16 [M][K], Bhg/Blg bf16 [N][K].
// Tile 128x128, BK=64, 256 threads (4 waves, 64x64 each = 4x4 frags of 16x16x32).
__device__ __forceinline__ void stage_tile(ushort_t* __restrict__ lds,
                                           const ushort_t* __restrict__ g, int K)
{
    // tile = 128 rows x 64 bf16; 1024 chunks of 16B; 4 chunks/thread, coalesced.
    const int tid = threadIdx.x;
    short8 v[4];
    #pragma unroll
    for (int i = 0; i < 4; ++i) {
        const int ch = i * 256 + tid;
        const int r = ch >> 3, c = ch & 7;
        v[i] = *(const short8*)(g + (size_t)r * K + c * 8);
    }
    #pragma unroll
    for (int i = 0; i < 4; ++i) {
        const int ch = i * 256 + tid;
        const int r = ch >> 3, c = ch & 7;
        *(short8*)&lds[r * 72 + c * 8] = v[i];
    }
}

__global__ __launch_bounds__(256)
void gemm_bf16x3(const ushort_t* __restrict__ Ahg, const ushort_t* __restrict__ Alg, int K,
                 const ushort_t* __restrict__ Bhg, const ushort_t* __restrict__ Blg,
                 float* __restrict__ Cbase, int chunkW, size_t chunkStride)
{
    constexpr int SK = 72;   // padded row stride (bf16): bank-clean for b128 ops
    __shared__ ushort_t Ah[128 * SK], Al[128 * SK], Bh[128 * SK], Bl[128 * SK];

    const int tid  = threadIdx.x;
    const int row0 = blockIdx.y * 128;
    const int col0 = blockIdx.x * 128;
    const int chunk = col0 / chunkW;
    const int lc0   = col0 - chunk * chunkW;
    float* __restrict__ C = Cbase + (size_t)chunk * chunkStride;

    const int w = tid >> 6, lane = tid & 63;
    const int wm = w >> 1, wn = w & 1;
    const int fr = lane & 15, kg = (lane >> 4) * 8;

    f32x4 acc[4][4] = {};

    for (int k0 = 0; k0 < K; k0 += 64) {
        stage_tile(Ah, Ahg + (size_t)row0 * K + k0, K);
        stage_tile(Al, Alg + (size_t)row0 * K + k0, K);
        stage_tile(Bh, Bhg + (size_t)col0 * K + k0, K);
        stage_tile(Bl, Blg + (size_t)col0 * K + k0, K);
        __syncthreads();

        #pragma unroll
        for (int ks = 0; ks < 2; ++ks) {
            const int kf = ks * 32 + kg;
            short8 a_h[4], a_l[4], b_h[4], b_l[4];
            #pragma unroll
            for (int i = 0; i < 4; ++i) {
                a_h[i] = *(const short8*)&Ah[(wm * 64 + i * 16 + fr) * SK + kf];
                a_l[i] = *(const short8*)&Al[(wm * 64 + i * 16 + fr) * SK + kf];
                b_h[i] = *(const short8*)&Bh[(wn * 64 + i * 16 + fr) * SK + kf];
                b_l[i] = *(const short8*)&Bl[(wn * 64 + i * 16 + fr) * SK + kf];
            }
            #pragma unroll
            for (int mi = 0; mi < 4; ++mi) {
                #pragma unroll
                for (int ni = 0; ni < 4; ++ni) {
                    acc[mi][ni] = __builtin_amdgcn_mfma_f32_16x16x32_bf16(a_h[mi], b_h[ni], acc[mi][ni], 0, 0, 0);
                    acc[mi][ni] = __builtin_amdgcn_mfma_f32_16x16x32_bf16(a_h[mi], b_l[ni], acc[mi][ni], 0, 0, 0);
                    acc[mi][ni] = __builtin_amdgcn_mfma_f32_16x16x32_bf16(a_l[mi], b_h[ni], acc[mi][ni], 0, 0, 0);
                }
            }
        }
        __syncthreads();
    }

    // epilogue: C/D layout col=lane&15, row=(lane>>4)*4+reg
    const int crow = (lane >> 4) * 4;
    #pragma unroll
    for (int mi = 0; mi < 4; ++mi) {
        const int gr = row0 + wm * 64 + mi * 16 + crow;
        #pragma unroll
        for (int ni = 0; ni < 4; ++ni) {
            const int gc = lc0 + wn * 64 + ni * 16 + fr;
            #pragma unroll
            for (int j = 0; j < 4; ++j)
                C[(size_t)(gr + j) * chunkW + gc] = acc[mi][ni][j];
        }
    }
}

// ---------------- sentinel fill (streaming stores) ----------------
__global__ __launch_bounds__(256)
void fill_kernel(float* __restrict__ dst, size_t n4)
{
    const float4 v = make_float4(MASKED_VAL, MASKED_VAL, MASKED_VAL, MASKED_VAL);
    size_t i = (size_t)blockIdx.x * 256 + threadIdx.x;
    const size_t stride = (size_t)gridDim.x * 256;
    for (; i < n4; i += stride)
        ((float4*)dst)[i] = v;
}

// ---------------- chain: compute dots + argmax, emit compact records ----------
template <int C, int P>
__device__ __forceinline__ int level_step_nc(const float* __restrict__ W,
                                             const float* zrow,
                                             volatile float* lcomp,
                                             int p, int lane,
                                             float* __restrict__ rec /*6 fl*/)
{
    const int cnt = (C - p + P - 1) / P;   // 3..5
    if (lane < cnt) {
        const float* wc = W + p + lane * P;
        float s0 = 0.f, s1 = 0.f, s2 = 0.f, s3 = 0.f;
        #pragma unroll 4
        for (int k = 0; k < 256; k += 4) {
            s0 = fmaf(zrow[k + 0], wc[(size_t)(k + 0) * C], s0);
            s1 = fmaf(zrow[k + 1], wc[(size_t)(k + 1) * C], s1);
            s2 = fmaf(zrow[k + 2], wc[(size_t)(k + 2) * C], s2);
            s3 = fmaf(zrow[k + 3], wc[(size_t)(k + 3) * C], s3);
        }
        lcomp[lane] = (s0 + s1) + (s2 + s3);
    }
    asm volatile("s_waitcnt lgkmcnt(0)" ::: "memory");

    float best = lcomp[0];
    int bj = 0;
    #pragma unroll
    for (int j = 1; j < 5; ++j) {
        if (j < cnt) {
            float vj = lcomp[j];
            if (vj > best) { best = vj; bj = j; }
        }
    }

    if (lane == 0) rec[0] = __int_as_float(p);
    if (lane >= 1 && lane <= 5) rec[lane] = (lane - 1 < cnt) ? lcomp[lane - 1] : 0.f;

    return p + bj * P;
}

__global__ __launch_bounds__(256)
void chain_kernel(const float* __restrict__ z,
                  const float* __restrict__ Wp, const float* __restrict__ Wo,
                  const float* __restrict__ Wf, const float* __restrict__ Wg,
                  const float* __restrict__ Ws,
                  float* __restrict__ out, float* __restrict__ compact)
{
    __shared__ float zsh[4][256];
    __shared__ float lcomp[4][8];

    const int w    = threadIdx.x >> 6;
    const int lane = threadIdx.x & 63;
    const size_t b = (size_t)blockIdx.x * 4 + w;

    const float* zr = z + b * 256;
    *(float4*)&zsh[w][lane * 4] = *(const float4*)(zr + lane * 4);
    asm volatile("s_waitcnt lgkmcnt(0)" ::: "memory");
    const float* zrow = &zsh[w][0];

    // phylum: 40 dense logits (unmasked), written directly
    float pv = MASKED_VAL;
    if (lane < 40) {
        float s0 = 0.f, s1 = 0.f, s2 = 0.f, s3 = 0.f;
        #pragma unroll 4
        for (int k = 0; k < 256; k += 4) {
            s0 = fmaf(zrow[k + 0], Wp[(k + 0) * 40 + lane], s0);
            s1 = fmaf(zrow[k + 1], Wp[(k + 1) * 40 + lane], s1);
            s2 = fmaf(zrow[k + 2], Wp[(k + 2) * 40 + lane], s2);
            s3 = fmaf(zrow[k + 3], Wp[(k + 3) * 40 + lane], s3);
        }
        pv = (s0 + s1) + (s2 + s3);
        out[OFF_LP + b * 40 + lane] = pv;
    }
    float v = pv;
    int idx = lane;
    #pragma unroll
    for (int off = 32; off; off >>= 1) {
        float ov = __shfl_xor(v, off);
        int   oi = __shfl_xor(idx, off);
        if (ov > v || (ov == v && oi < idx)) { v = ov; idx = oi; }
    }
    int p = idx;

    p = level_step_nc<200, 40>   (Wo, zrow, lcomp[w], p, lane, compact + (0 * Bn + b) * 6);
    p = level_step_nc<800, 200>  (Wf, zrow, lcomp[w], p, lane, compact + (1 * Bn + b) * 6);
    p = level_step_nc<3000, 800> (Wg, zrow, lcomp[w], p, lane, compact + (2 * Bn + b) * 6);
    (void)level_step_nc<12000, 3000>(Ws, zrow, lcomp[w], p, lane, compact + (3 * Bn + b) * 6);
}

// ---------------- scatter valid logits over the sentinel fill ----------------
__global__ __launch_bounds__(256)
void scatter_kernel(const float* __restrict__ compact, float* __restrict__ out)
{
    const int t = blockIdx.x * 256 + threadIdx.x;
    if (t >= 4 * Bn) return;
    const int lvl = t >> 13, b = t & (Bn - 1);
    const int Cs[4] = {200, 800, 3000, 12000};
    const int Ps[4] = {40, 200, 800, 3000};
    const size_t OFFL[4] = {OFF_LO, OFF_LF, OFF_LG, OFF_LS};
    const float* rec = compact + ((size_t)lvl * Bn + b) * 6;
    const int p = __float_as_int(rec[0]);
    const int C = Cs[lvl], P = Ps[lvl];
    const int cnt = (C - p + P - 1) / P;
    float* dst = out + OFFL[lvl] + (size_t)b * C;
    for (int j = 0; j < cnt; ++j)
        dst[p + j * P] = rec[1 + j];
}

// ---------------- host launcher ----------------
extern "C" void kernel_launch(void* const* d_in, const int* in_sizes, int n_in,
                              void* d_out, int out_size, void* d_ws, size_t ws_size,
                              hipStream_t stream)
{
    const float* seq    = (const float*)d_in[0];
    const float* Wdna   = (const float*)d_in[1];
    const float* Wenc   = (const float*)d_in[2];
    const float* Wcls_p = (const float*)d_in[3];
    const float* Wdec_p = (const float*)d_in[4];
    const float* Wcls_o = (const float*)d_in[5];
    const float* Wdec_o = (const float*)d_in[6];
    const float* Wcls_f = (const float*)d_in[7];
    const float* Wdec_f = (const float*)d_in[8];
    const float* Wcls_g = (const float*)d_in[9];
    const float* Wdec_g = (const float*)d_in[10];
    const float* Wcls_s = (const float*)d_in[11];
    const float* Wdec_s = (const float*)d_in[12];
    const float* Wglob  = (const float*)d_in[13];
    (void)in_sizes; (void)n_in; (void)out_size; (void)ws_size;

    float* out = (float*)d_out;
    ushort_t* ws = (ushort_t*)d_ws;

    ushort_t* seqH = (ushort_t*)(out + S_SEQ_H);
    ushort_t* seqL = (ushort_t*)(out + S_SEQ_L);
    ushort_t* embH = (ushort_t*)(out + S_EMB_H);
    ushort_t* embL = (ushort_t*)(out + S_EMB_L);
    ushort_t* zH   = (ushort_t*)(out + S_Z_H);
    ushort_t* zL   = (ushort_t*)(out + S_Z_L);
    ushort_t* recH = (ushort_t*)(out + S_REC_H);
    ushort_t* recL = (ushort_t*)(out + S_REC_L);
    ushort_t* dnaH = ws + WS_DNA_H;
    ushort_t* dnaL = ws + WS_DNA_L;
    ushort_t* encH = ws + WS_ENC_H;
    ushort_t* encL = ws + WS_ENC_L;
    float* compact = (float*)ws + WS_COMPACT_FL;

    // --- weight preps ---
    prep_wt<1024, 768><<<2048, 256, 0, stream>>>(Wdna, dnaH, dnaL);
    prep_wt<768, 256><<<768, 256, 0, stream>>>(Wenc, encH, encL);
    Ptr6 s6{{Wdec_p, Wdec_o, Wdec_f, Wdec_g, Wdec_s, Wglob}};
    prep_rec<<<2048, 256, 0, stream>>>(s6, recH, recL);
    // seq split: 8192*1024/8 = 1048576 chunks
    split_f32<<<4096, 256, 0, stream>>>(seq, seqH, seqL, Bn * SEQ / 8);

    // --- emb = seq @ Wdna ---
    gemm_bf16x3<<<dim3(EMB / 128, Bn / 128), 256, 0, stream>>>(
        seqH, seqL, SEQ, dnaH, dnaL, out + OFF_EMB, EMB, 0);
    split_f32<<<3072, 256, 0, stream>>>(out + OFF_EMB, embH, embL, Bn * EMB / 8);

    // --- z = emb @ Wenc ---
    gemm_bf16x3<<<dim3(LAT / 128, Bn / 128), 256, 0, stream>>>(
        embH, embL, EMB, encH, encL, out + OFF_Z, LAT, 0);
    split_f32<<<1024, 256, 0, stream>>>(out + OFF_Z, zH, zL, Bn * LAT / 8);

    // --- fused recons + global: z @ [Wdec_p|...|Wglob] ---
    gemm_bf16x3<<<dim3(4608 / 128, Bn / 128), 256, 0, stream>>>(
        zH, zL, LAT, recH, recL, out + OFF_RP, EMB, (size_t)Bn * EMB);

    // --- chain compute (before fill: reads nothing in the fill window) ---
    chain_kernel<<<dim3(Bn / 4), 256, 0, stream>>>(out + OFF_Z, Wcls_p, Wcls_o, Wcls_f,
                                                   Wcls_g, Wcls_s, out, compact);

    // --- sentinel fill over the whole masked-logit region, then scatter ---
    fill_kernel<<<2048, 256, 0, stream>>>(out + OFF_LO, FILL_N / 4);
    scatter_kernel<<<(4 * Bn + 255) / 256, 256, 0, stream>>>(compact, out);
}

// Round 5
// 442.213 us; speedup vs baseline: 1.1799x; 1.1799x over previous
//
#include <hip/hip_runtime.h>
#include <hip/hip_bf16.h>

typedef __attribute__((ext_vector_type(8))) short short8;
typedef __attribute__((ext_vector_type(4))) float f32x4;
typedef unsigned short ushort_t;
typedef unsigned int u32;

// ---------------- problem constants ----------------
static constexpr int Bn  = 8192;
static constexpr int SEQ = 1024;
static constexpr int EMB = 768;
static constexpr int LAT = 256;

// output offsets (floats): (z, Lp, Lo, Lf, Lg, Ls, Rp, Ro, Rf, Rg, Rs, glob, emb)
static constexpr size_t OFF_Z   = 0;
static constexpr size_t OFF_LP  = 2097152;
static constexpr size_t OFF_LO  = 2424832;
static constexpr size_t OFF_LF  = 4063232;
static constexpr size_t OFF_LG  = 10616832;
static constexpr size_t OFF_LS  = 35192832;
static constexpr size_t OFF_RP  = 133496832;  // Rp..Rs,glob contiguous, stride 8192*768
static constexpr size_t OFF_EMB = 171245568;

// Scratch inside the masked-logit region [OFF_LO, OFF_RP) (131,072,000 floats),
// which is sentinel-filled LATE. Float offsets:
static constexpr size_t SCR      = OFF_LO;
static constexpr size_t S_SEQ_H  = SCR + 0;         // 8192x1024 bf16 tiles
static constexpr size_t S_SEQ_L  = SCR + 4194304;
static constexpr size_t S_EMB_H  = SCR + 8388608;   // 8192x768
static constexpr size_t S_EMB_L  = SCR + 11534336;
static constexpr size_t S_Z_H    = SCR + 14680064;  // 8192x256
static constexpr size_t S_Z_L    = SCR + 15728640;
static constexpr size_t S_REC_H  = SCR + 16777216;  // 4608x256
static constexpr size_t S_REC_L  = SCR + 17367040;  // end 17956864
static constexpr size_t S_CLS_T  = SCR + 17956864;  // transposed W_cls (f32)
static constexpr size_t S_T_O    = S_CLS_T + 0;        // 200*256
static constexpr size_t S_T_F    = S_CLS_T + 51200;    // 800*256
static constexpr size_t S_T_G    = S_CLS_T + 256000;   // 3000*256
static constexpr size_t S_T_S    = S_CLS_T + 1024000;  // 12000*256 -> end 22052864

// d_ws layout (ushort units); <= 4.72 MB used (8.65 MB proven safe in R2/R3).
static constexpr size_t WS_DNA_H = 0;        // 768x1024 tiles
static constexpr size_t WS_DNA_L = 786432;
static constexpr size_t WS_ENC_H = 1572864;  // 256x768 tiles
static constexpr size_t WS_ENC_L = 1769472;
static constexpr size_t WS_COMPACT_FL = 983040; // float offset: 4 x 8192 x 6

#define MASKED_VAL (-1.0e30f)
static constexpr size_t FILL_N = OFF_RP - OFF_LO;   // 131072000 floats

// ---------------- bf16 split helpers (RNE) ----------------
__device__ __forceinline__ ushort_t bfbits(float f) {
    return __builtin_bit_cast(ushort_t, __float2bfloat16(f));
}
__device__ __forceinline__ float bf2f(ushort_t h) {
    return __builtin_bit_cast(float, ((unsigned)h) << 16);
}
__device__ __forceinline__ void split2(float f, ushort_t& h, ushort_t& l) {
    h = bfbits(f);
    l = bfbits(f - bf2f(h));
}

// Tiled-swizzled operand layout: tiles of 128 rows x 64 k (bf16), tile-major
// [rowTile][kTile]; within tile, 16B granule g of row r sits at granule (g^(r&7)).
// This IS the LDS image: global_load_lds streams it linearly; ds_read_b128 XORs
// the same bits -> 2-way bank aliasing (free, m136).
__device__ __forceinline__ size_t tile_pos(int rt, int nKT, int kt, int r, int g) {
    return ((size_t)rt * nKT + kt) * 8192 + (size_t)r * 64 + ((g ^ (r & 7)) << 3);
}

// ---------------- prep: linear f32 [M][K] -> hi/lo swizzled tiles ----------------
__global__ __launch_bounds__(256)
void split_tiled(const float* __restrict__ src, ushort_t* __restrict__ dh,
                 ushort_t* __restrict__ dl, int M, int K)
{
    const int gpr = K >> 3;      // 16B granules per row
    const int nKT = K >> 6;
    const int nG  = M * gpr;
    for (int gi = blockIdx.x * 256 + threadIdx.x; gi < nG; gi += gridDim.x * 256) {
        const int row = gi / gpr, gk = gi - row * gpr;
        const float* s = src + (size_t)row * K + gk * 8;
        const float4 a = *(const float4*)s;
        const float4 b = *(const float4*)(s + 4);
        const float f[8] = {a.x, a.y, a.z, a.w, b.x, b.y, b.z, b.w};
        short8 hh, ll;
        #pragma unroll
        for (int j = 0; j < 8; ++j) {
            ushort_t hv, lv;
            split2(f[j], hv, lv);
            hh[j] = (short)hv; ll[j] = (short)lv;
        }
        const size_t base = tile_pos(row >> 7, nKT, gk >> 3, row & 127, gk & 7);
        *(short8*)(dh + base) = hh;
        *(short8*)(dl + base) = ll;
    }
}

// ---------------- prep: f32 [K][N] weights -> hi/lo swizzled tiles over N rows ----
template <int K, int N>
__global__ void prep_wtT(const float* __restrict__ src, ushort_t* __restrict__ dh,
                         ushort_t* __restrict__ dl)
{
    constexpr int gpr = K >> 3, nKT = K >> 6;
    const int nG = N * gpr;
    for (int gi = blockIdx.x * 256 + threadIdx.x; gi < nG; gi += gridDim.x * 256) {
        const int n = gi / gpr, gk = gi - n * gpr;
        short8 hh, ll;
        #pragma unroll
        for (int j = 0; j < 8; ++j) {
            ushort_t hv, lv;
            split2(src[(size_t)(gk * 8 + j) * N + n], hv, lv);
            hh[j] = (short)hv; ll[j] = (short)lv;
        }
        const size_t base = tile_pos(n >> 7, nKT, gk >> 3, n & 127, gk & 7);
        *(short8*)(dh + base) = hh;
        *(short8*)(dl + base) = ll;
    }
}

struct Ptr6 { const float* p[6]; };
__global__ void prep_recT(Ptr6 s, ushort_t* __restrict__ dh, ushort_t* __restrict__ dl)
{
    constexpr int gpr = 32, nKT = 4;   // K = 256
    const int nG = 4608 * gpr;
    for (int gi = blockIdx.x * 256 + threadIdx.x; gi < nG; gi += gridDim.x * 256) {
        const int np = gi / gpr, gk = gi - np * gpr;
        const int m = np / 768, nn = np - m * 768;
        const float* sm = s.p[m];
        short8 hh, ll;
        #pragma unroll
        for (int j = 0; j < 8; ++j) {
            ushort_t hv, lv;
            split2(sm[(size_t)(gk * 8 + j) * 768 + nn], hv, lv);
            hh[j] = (short)hv; ll[j] = (short)lv;
        }
        const size_t base = tile_pos(np >> 7, nKT, gk >> 3, np & 127, gk & 7);
        *(short8*)(dh + base) = hh;
        *(short8*)(dl + base) = ll;
    }
}

// ---------------- prep: transpose W_cls [256][C] -> [C][256] ----------------
__global__ __launch_bounds__(256)
void transpose_cls(const float* __restrict__ src, float* __restrict__ dst, int C)
{
    const int n = 256 * C;
    for (int i = blockIdx.x * 256 + threadIdx.x; i < n; i += gridDim.x * 256) {
        const int c = i >> 8, k = i & 255;
        dst[i] = src[(size_t)k * C + c];   // coalesced writes, gathered reads (L2)
    }
}

// ---------------- bf16x3 GEMM with global_load_lds + swizzled tiles ----------------
__device__ __forceinline__ void gload16(const ushort_t* g, ushort_t* l) {
    __builtin_amdgcn_global_load_lds(
        (const __attribute__((address_space(1))) u32*)g,
        (__attribute__((address_space(3))) u32*)l, 16, 0, 0);
}

__global__ __launch_bounds__(256)
void gemm_ts(const ushort_t* __restrict__ Ahg, const ushort_t* __restrict__ Alg,
             const ushort_t* __restrict__ Bhg, const ushort_t* __restrict__ Blg,
             int K, float* __restrict__ Cbase, int chunkW, size_t chunkStride)
{
    __shared__ ushort_t sAh[8192], sAl[8192], sBh[8192], sBl[8192];   // 64 KB

    const int tid = threadIdx.x, w = tid >> 6, lane = tid & 63;
    const int wm = w >> 1, wn = w & 1;
    const int fr = lane & 15, kg = lane >> 4;
    const int nKT = K >> 6;
    const int rt = blockIdx.y, ct = blockIdx.x;
    const int col0 = ct * 128;
    const int chunk = col0 / chunkW;
    const int lc0 = col0 - chunk * chunkW;
    float* __restrict__ C = Cbase + (size_t)chunk * chunkStride;

    const int sbase = w * 2048;       // wave's 4 chunks x 512 ushorts
    const int lgo = lane * 8;         // lane offset within a 1KB chunk (ushorts)

    f32x4 acc[4][4] = {};

    for (int kt = 0; kt < nKT; ++kt) {
        const size_t at = ((size_t)rt * nKT + kt) * 8192;
        const size_t bt = ((size_t)ct * nKT + kt) * 8192;
        #pragma unroll
        for (int i = 0; i < 4; ++i) {
            const int co = sbase + i * 512;
            gload16(Ahg + at + co + lgo, &sAh[co]);
            gload16(Alg + at + co + lgo, &sAl[co]);
            gload16(Bhg + bt + co + lgo, &sBh[co]);
            gload16(Blg + bt + co + lgo, &sBl[co]);
        }
        __syncthreads();   // drains vmcnt -> tiles resident

        #pragma unroll
        for (int ks = 0; ks < 2; ++ks) {
            const int g = ks * 4 + kg;
            short8 a_h[4], a_l[4], b_h[4], b_l[4];
            #pragma unroll
            for (int i = 0; i < 4; ++i) {
                const int ra = wm * 64 + i * 16 + fr;
                const int pa = ra * 64 + ((g ^ (ra & 7)) << 3);
                a_h[i] = *(const short8*)&sAh[pa];
                a_l[i] = *(const short8*)&sAl[pa];
                const int rb = wn * 64 + i * 16 + fr;
                const int pb = rb * 64 + ((g ^ (rb & 7)) << 3);
                b_h[i] = *(const short8*)&sBh[pb];
                b_l[i] = *(const short8*)&sBl[pb];
            }
            #pragma unroll
            for (int mi = 0; mi < 4; ++mi) {
                #pragma unroll
                for (int ni = 0; ni < 4; ++ni) {
                    acc[mi][ni] = __builtin_amdgcn_mfma_f32_16x16x32_bf16(a_h[mi], b_h[ni], acc[mi][ni], 0, 0, 0);
                    acc[mi][ni] = __builtin_amdgcn_mfma_f32_16x16x32_bf16(a_h[mi], b_l[ni], acc[mi][ni], 0, 0, 0);
                    acc[mi][ni] = __builtin_amdgcn_mfma_f32_16x16x32_bf16(a_l[mi], b_h[ni], acc[mi][ni], 0, 0, 0);
                }
            }
        }
        __syncthreads();   // protect LDS before next stage
    }

    // epilogue: C/D layout col=lane&15, row=(lane>>4)*4+reg
    const int crow = kg * 4;
    #pragma unroll
    for (int mi = 0; mi < 4; ++mi) {
        const int gr = rt * 128 + wm * 64 + mi * 16 + crow;
        #pragma unroll
        for (int ni = 0; ni < 4; ++ni) {
            const int gc = lc0 + wn * 64 + ni * 16 + fr;
            #pragma unroll
            for (int j = 0; j < 4; ++j)
                C[(size_t)(gr + j) * chunkW + gc] = acc[mi][ni][j];
        }
    }
}

// ---------------- sentinel fill (streaming stores) ----------------
__global__ __launch_bounds__(256)
void fill_kernel(float* __restrict__ dst, size_t n4)
{
    const float4 v = make_float4(MASKED_VAL, MASKED_VAL, MASKED_VAL, MASKED_VAL);
    size_t i = (size_t)blockIdx.x * 256 + threadIdx.x;
    const size_t stride = (size_t)gridDim.x * 256;
    for (; i < n4; i += stride)
        ((float4*)dst)[i] = v;
}

// ---------------- chain: dots from transposed W_cls + argmax + compact ---------
template <int C, int P>
__device__ __forceinline__ int level_step_t(const float* __restrict__ WT,  // [C][256]
                                            const float* zrow,
                                            volatile float* lcomp,
                                            int p, int lane,
                                            float* __restrict__ rec /*6 fl*/)
{
    const int cnt = (C - p + P - 1) / P;   // 3..5
    if (lane < cnt) {
        const int c = p + lane * P;
        const float4* wv = (const float4*)(WT + (size_t)c * 256);
        float4 s0 = {0,0,0,0}, s1 = {0,0,0,0};
        #pragma unroll 8
        for (int q = 0; q < 64; q += 2) {
            const float4 w0 = wv[q], w1 = wv[q + 1];
            const float4 z0 = *(const float4*)&zrow[q * 4];
            const float4 z1 = *(const float4*)&zrow[q * 4 + 4];
            s0.x = fmaf(w0.x, z0.x, s0.x); s0.y = fmaf(w0.y, z0.y, s0.y);
            s0.z = fmaf(w0.z, z0.z, s0.z); s0.w = fmaf(w0.w, z0.w, s0.w);
            s1.x = fmaf(w1.x, z1.x, s1.x); s1.y = fmaf(w1.y, z1.y, s1.y);
            s1.z = fmaf(w1.z, z1.z, s1.z); s1.w = fmaf(w1.w, z1.w, s1.w);
        }
        lcomp[lane] = ((s0.x + s0.y) + (s0.z + s0.w)) + ((s1.x + s1.y) + (s1.z + s1.w));
    }
    asm volatile("s_waitcnt lgkmcnt(0)" ::: "memory");

    float best = lcomp[0];
    int bj = 0;
    #pragma unroll
    for (int j = 1; j < 5; ++j) {
        if (j < cnt) {
            float vj = lcomp[j];
            if (vj > best) { best = vj; bj = j; }
        }
    }

    if (lane == 0) rec[0] = __int_as_float(p);
    if (lane >= 1 && lane <= 5) rec[lane] = (lane - 1 < cnt) ? lcomp[lane - 1] : 0.f;

    return p + bj * P;
}

__global__ __launch_bounds__(256)
void chain_kernel(const float* __restrict__ z,
                  const float* __restrict__ Wp,   // [256][40] original
                  const float* __restrict__ ToT, const float* __restrict__ TfT,
                  const float* __restrict__ TgT, const float* __restrict__ TsT,
                  float* __restrict__ out, float* __restrict__ compact)
{
    __shared__ float zsh[4][256];
    __shared__ float lcomp[4][8];

    const int w    = threadIdx.x >> 6;
    const int lane = threadIdx.x & 63;
    const size_t b = (size_t)blockIdx.x * 4 + w;

    const float* zr = z + b * 256;
    *(float4*)&zsh[w][lane * 4] = *(const float4*)(zr + lane * 4);
    asm volatile("s_waitcnt lgkmcnt(0)" ::: "memory");
    const float* zrow = &zsh[w][0];

    // phylum: 40 dense logits (unmasked) — unchanged numerics from R2-R4
    float pv = MASKED_VAL;
    if (lane < 40) {
        float s0 = 0.f, s1 = 0.f, s2 = 0.f, s3 = 0.f;
        #pragma unroll 4
        for (int k = 0; k < 256; k += 4) {
            s0 = fmaf(zrow[k + 0], Wp[(k + 0) * 40 + lane], s0);
            s1 = fmaf(zrow[k + 1], Wp[(k + 1) * 40 + lane], s1);
            s2 = fmaf(zrow[k + 2], Wp[(k + 2) * 40 + lane], s2);
            s3 = fmaf(zrow[k + 3], Wp[(k + 3) * 40 + lane], s3);
        }
        pv = (s0 + s1) + (s2 + s3);
        out[OFF_LP + b * 40 + lane] = pv;
    }
    float v = pv;
    int idx = lane;
    #pragma unroll
    for (int off = 32; off; off >>= 1) {
        float ov = __shfl_xor(v, off);
        int   oi = __shfl_xor(idx, off);
        if (ov > v || (ov == v && oi < idx)) { v = ov; idx = oi; }
    }
    int p = idx;

    p = level_step_t<200, 40>    (ToT, zrow, lcomp[w], p, lane, compact + (0 * Bn + b) * 6);
    p = level_step_t<800, 200>   (TfT, zrow, lcomp[w], p, lane, compact + (1 * Bn + b) * 6);
    p = level_step_t<3000, 800>  (TgT, zrow, lcomp[w], p, lane, compact + (2 * Bn + b) * 6);
    (void)level_step_t<12000, 3000>(TsT, zrow, lcomp[w], p, lane, compact + (3 * Bn + b) * 6);
}

// ---------------- scatter valid logits over the sentinel fill ----------------
__global__ __launch_bounds__(256)
void scatter_kernel(const float* __restrict__ compact, float* __restrict__ out)
{
    const int t = blockIdx.x * 256 + threadIdx.x;
    if (t >= 4 * Bn) return;
    const int lvl = t >> 13, b = t & (Bn - 1);
    const int Cs[4] = {200, 800, 3000, 12000};
    const int Ps[4] = {40, 200, 800, 3000};
    const size_t OFFL[4] = {OFF_LO, OFF_LF, OFF_LG, OFF_LS};
    const float* rec = compact + ((size_t)lvl * Bn + b) * 6;
    const int p = __float_as_int(rec[0]);
    const int C = Cs[lvl], P = Ps[lvl];
    const int cnt = (C - p + P - 1) / P;
    float* dst = out + OFFL[lvl] + (size_t)b * C;
    for (int j = 0; j < cnt; ++j)
        dst[p + j * P] = rec[1 + j];
}

// ---------------- host launcher ----------------
extern "C" void kernel_launch(void* const* d_in, const int* in_sizes, int n_in,
                              void* d_out, int out_size, void* d_ws, size_t ws_size,
                              hipStream_t stream)
{
    const float* seq    = (const float*)d_in[0];
    const float* Wdna   = (const float*)d_in[1];
    const float* Wenc   = (const float*)d_in[2];
    const float* Wcls_p = (const float*)d_in[3];
    const float* Wdec_p = (const float*)d_in[4];
    const float* Wcls_o = (const float*)d_in[5];
    const float* Wdec_o = (const float*)d_in[6];
    const float* Wcls_f = (const float*)d_in[7];
    const float* Wdec_f = (const float*)d_in[8];
    const float* Wcls_g = (const float*)d_in[9];
    const float* Wdec_g = (const float*)d_in[10];
    const float* Wcls_s = (const float*)d_in[11];
    const float* Wdec_s = (const float*)d_in[12];
    const float* Wglob  = (const float*)d_in[13];
    (void)in_sizes; (void)n_in; (void)out_size; (void)ws_size;

    float* out = (float*)d_out;
    ushort_t* ws = (ushort_t*)d_ws;

    ushort_t* seqH = (ushort_t*)(out + S_SEQ_H);
    ushort_t* seqL = (ushort_t*)(out + S_SEQ_L);
    ushort_t* embH = (ushort_t*)(out + S_EMB_H);
    ushort_t* embL = (ushort_t*)(out + S_EMB_L);
    ushort_t* zH   = (ushort_t*)(out + S_Z_H);
    ushort_t* zL   = (ushort_t*)(out + S_Z_L);
    ushort_t* recH = (ushort_t*)(out + S_REC_H);
    ushort_t* recL = (ushort_t*)(out + S_REC_L);
    float* ToT = out + S_T_O;
    float* TfT = out + S_T_F;
    float* TgT = out + S_T_G;
    float* TsT = out + S_T_S;
    ushort_t* dnaH = ws + WS_DNA_H;
    ushort_t* dnaL = ws + WS_DNA_L;
    ushort_t* encH = ws + WS_ENC_H;
    ushort_t* encL = ws + WS_ENC_L;
    float* compact = (float*)ws + WS_COMPACT_FL;

    // --- preps: swizzled-tile weight splits + cls transposes + seq split ---
    prep_wtT<1024, 768><<<384, 256, 0, stream>>>(Wdna, dnaH, dnaL);
    prep_wtT<768, 256><<<96, 256, 0, stream>>>(Wenc, encH, encL);
    Ptr6 s6{{Wdec_p, Wdec_o, Wdec_f, Wdec_g, Wdec_s, Wglob}};
    prep_recT<<<576, 256, 0, stream>>>(s6, recH, recL);
    split_tiled<<<4096, 256, 0, stream>>>(seq, seqH, seqL, Bn, SEQ);
    transpose_cls<<<200, 256, 0, stream>>>(Wcls_o, ToT, 200);
    transpose_cls<<<800, 256, 0, stream>>>(Wcls_f, TfT, 800);
    transpose_cls<<<1500, 256, 0, stream>>>(Wcls_g, TgT, 3000);
    transpose_cls<<<2048, 256, 0, stream>>>(Wcls_s, TsT, 12000);

    // --- emb = seq @ Wdna ---
    gemm_ts<<<dim3(EMB / 128, Bn / 128), 256, 0, stream>>>(
        seqH, seqL, dnaH, dnaL, SEQ, out + OFF_EMB, EMB, 0);
    split_tiled<<<3072, 256, 0, stream>>>(out + OFF_EMB, embH, embL, Bn, EMB);

    // --- z = emb @ Wenc ---
    gemm_ts<<<dim3(LAT / 128, Bn / 128), 256, 0, stream>>>(
        embH, embL, encH, encL, EMB, out + OFF_Z, LAT, 0);
    split_tiled<<<1024, 256, 0, stream>>>(out + OFF_Z, zH, zL, Bn, LAT);

    // --- fused recons + global: z @ [Wdec_p|...|Wglob] ---
    gemm_ts<<<dim3(4608 / 128, Bn / 128), 256, 0, stream>>>(
        zH, zL, recH, recL, LAT, out + OFF_RP, EMB, (size_t)Bn * EMB);

    // --- chain compute (reads scratch; must precede fill) ---
    chain_kernel<<<dim3(Bn / 4), 256, 0, stream>>>(out + OFF_Z, Wcls_p, ToT, TfT,
                                                   TgT, TsT, out, compact);

    // --- sentinel fill over the masked-logit region, then scatter ---
    fill_kernel<<<2048, 256, 0, stream>>>(out + OFF_LO, FILL_N / 4);
    scatter_kernel<<<(4 * Bn + 255) / 256, 256, 0, stream>>>(compact, out);
}

// Round 7
// 410.435 us; speedup vs baseline: 1.2713x; 1.0774x over previous
//
#include <hip/hip_runtime.h>
#include <hip/hip_bf16.h>

typedef __attribute__((ext_vector_type(8))) short short8;
typedef __attribute__((ext_vector_type(4))) float f32x4;
typedef unsigned short ushort_t;
typedef unsigned int u32;

// ---------------- problem constants ----------------
static constexpr int Bn  = 8192;
static constexpr int SEQ = 1024;
static constexpr int EMB = 768;
static constexpr int LAT = 256;

// output offsets (floats): (z, Lp, Lo, Lf, Lg, Ls, Rp, Ro, Rf, Rg, Rs, glob, emb)
static constexpr size_t OFF_Z   = 0;
static constexpr size_t OFF_LP  = 2097152;
static constexpr size_t OFF_LO  = 2424832;
static constexpr size_t OFF_LF  = 4063232;
static constexpr size_t OFF_LG  = 10616832;
static constexpr size_t OFF_LS  = 35192832;
static constexpr size_t OFF_RP  = 133496832;  // Rp..Rs,glob contiguous, stride 8192*768
static constexpr size_t OFF_EMB = 171245568;

// Scratch inside the masked-logit region [OFF_LO, OFF_RP) (131,072,000 floats).
static constexpr size_t SCR      = OFF_LO;
static constexpr size_t S_SEQ_H  = SCR + 0;         // 8192x1024 bf16 tiles
static constexpr size_t S_SEQ_L  = SCR + 4194304;
static constexpr size_t S_EMB_H  = SCR + 8388608;   // 8192x768
static constexpr size_t S_EMB_L  = SCR + 11534336;
static constexpr size_t S_Z_H    = SCR + 14680064;  // 8192x256
static constexpr size_t S_Z_L    = SCR + 15728640;
static constexpr size_t S_REC_H  = SCR + 16777216;  // 4608x256
static constexpr size_t S_REC_L  = SCR + 17367040;  // end 17956864
static constexpr size_t S_CLS_T  = SCR + 17956864;  // transposed W_cls (f32)
static constexpr size_t S_T_O    = S_CLS_T + 0;        // 200*256
static constexpr size_t S_T_F    = S_CLS_T + 51200;    // 800*256
static constexpr size_t S_T_G    = S_CLS_T + 256000;   // 3000*256
static constexpr size_t S_T_S    = S_CLS_T + 1024000;  // 12000*256 -> end SCR+22052864

// Fill plan (float4 units). Each span becomes writable once its readers finish:
//   fill-A: non-scratch tail [SCR+22052864, OFF_RP)  -> fused into emb GEMM
//   fill-Z: seqH/L           [SCR, SCR+8388608)      -> fused into z GEMM
//   fill-R: embH/L           [SCR+8388608, +14680064)-> fused into recon GEMM
//   fill-B: z/rec/cls_T      [SCR+14680064, +22052864) -> after chain (standalone)
static constexpr size_t SCR_END   = SCR + 22052864;
static constexpr size_t FILLA_N4  = (OFF_RP - SCR_END) / 4;        // 27254784 (436MB)
static constexpr size_t FILLZ_N4  = 8388608 / 4;                   // 2097152  (33.5MB)
static constexpr size_t FILLR_N4  = (14680064 - 8388608) / 4;      // 1572864  (25MB)
static constexpr size_t FILLB_N4  = (22052864 - 14680064) / 4;     // 1843200  (29.5MB)

// d_ws layout (ushort units); <= 4.72 MB used (8.65 MB proven safe in R2/R3).
static constexpr size_t WS_DNA_H = 0;        // 768x1024 tiles
static constexpr size_t WS_DNA_L = 786432;
static constexpr size_t WS_ENC_H = 1572864;  // 256x768 tiles
static constexpr size_t WS_ENC_L = 1769472;
static constexpr size_t WS_COMPACT_FL = 983040; // float offset: 4 x 8192 x 6

#define MASKED_VAL (-1.0e30f)

// ---------------- bf16 split helpers (RNE) ----------------
__device__ __forceinline__ ushort_t bfbits(float f) {
    return __builtin_bit_cast(ushort_t, __float2bfloat16(f));
}
__device__ __forceinline__ float bf2f(ushort_t h) {
    return __builtin_bit_cast(float, ((unsigned)h) << 16);
}
__device__ __forceinline__ void split2(float f, ushort_t& h, ushort_t& l) {
    h = bfbits(f);
    l = bfbits(f - bf2f(h));
}

// Tiled-swizzled operand layout: tiles of 128 rows x 64 k (bf16), tile-major
// [rowTile][kTile]; within tile, 16B granule g of row r sits at granule (g^(r&7)).
__device__ __forceinline__ size_t tile_pos(int rt, int nKT, int kt, int r, int g) {
    return ((size_t)rt * nKT + kt) * 8192 + (size_t)r * 64 + ((g ^ (r & 7)) << 3);
}

// ---------------- prep: linear f32 [M][K] -> hi/lo swizzled tiles ----------------
__global__ __launch_bounds__(256)
void split_tiled(const float* __restrict__ src, ushort_t* __restrict__ dh,
                 ushort_t* __restrict__ dl, int M, int K)
{
    const int gpr = K >> 3;
    const int nKT = K >> 6;
    const int nG  = M * gpr;
    for (int gi = blockIdx.x * 256 + threadIdx.x; gi < nG; gi += gridDim.x * 256) {
        const int row = gi / gpr, gk = gi - row * gpr;
        const float* s = src + (size_t)row * K + gk * 8;
        const float4 a = *(const float4*)s;
        const float4 b = *(const float4*)(s + 4);
        const float f[8] = {a.x, a.y, a.z, a.w, b.x, b.y, b.z, b.w};
        short8 hh, ll;
        #pragma unroll
        for (int j = 0; j < 8; ++j) {
            ushort_t hv, lv;
            split2(f[j], hv, lv);
            hh[j] = (short)hv; ll[j] = (short)lv;
        }
        const size_t base = tile_pos(row >> 7, nKT, gk >> 3, row & 127, gk & 7);
        *(short8*)(dh + base) = hh;
        *(short8*)(dl + base) = ll;
    }
}

// ---------------- prep: f32 [K][N] weights -> hi/lo swizzled tiles over N rows ----
template <int K, int N>
__global__ void prep_wtT(const float* __restrict__ src, ushort_t* __restrict__ dh,
                         ushort_t* __restrict__ dl)
{
    constexpr int gpr = K >> 3, nKT = K >> 6;
    const int nG = N * gpr;
    for (int gi = blockIdx.x * 256 + threadIdx.x; gi < nG; gi += gridDim.x * 256) {
        const int n = gi / gpr, gk = gi - n * gpr;
        short8 hh, ll;
        #pragma unroll
        for (int j = 0; j < 8; ++j) {
            ushort_t hv, lv;
            split2(src[(size_t)(gk * 8 + j) * N + n], hv, lv);
            hh[j] = (short)hv; ll[j] = (short)lv;
        }
        const size_t base = tile_pos(n >> 7, nKT, gk >> 3, n & 127, gk & 7);
        *(short8*)(dh + base) = hh;
        *(short8*)(dl + base) = ll;
    }
}

struct Ptr6 { const float* p[6]; };
__global__ void prep_recT(Ptr6 s, ushort_t* __restrict__ dh, ushort_t* __restrict__ dl)
{
    constexpr int gpr = 32, nKT = 4;   // K = 256
    const int nG = 4608 * gpr;
    for (int gi = blockIdx.x * 256 + threadIdx.x; gi < nG; gi += gridDim.x * 256) {
        const int np = gi / gpr, gk = gi - np * gpr;
        const int m = np / 768, nn = np - m * 768;
        const float* sm = s.p[m];
        short8 hh, ll;
        #pragma unroll
        for (int j = 0; j < 8; ++j) {
            ushort_t hv, lv;
            split2(sm[(size_t)(gk * 8 + j) * 768 + nn], hv, lv);
            hh[j] = (short)hv; ll[j] = (short)lv;
        }
        const size_t base = tile_pos(np >> 7, nKT, gk >> 3, np & 127, gk & 7);
        *(short8*)(dh + base) = hh;
        *(short8*)(dl + base) = ll;
    }
}

// ---------------- prep: LDS-tiled transpose W_cls [256][C] -> [C][256] ----------
__global__ __launch_bounds__(256)
void transpose_cls(const float* __restrict__ src, float* __restrict__ dst, int C)
{
    __shared__ float t[64][65];
    const int tid = threadIdx.x;
    const int kt  = blockIdx.y;          // 0..3 (k tile of 64 within 256)
    const int c0  = blockIdx.x * 64;
    const int cl  = tid & 63;
    const int kr  = tid >> 6;            // 0..3
    #pragma unroll
    for (int i = 0; i < 16; ++i) {
        const int k = i * 4 + kr;
        const int c = c0 + cl;
        t[k][cl] = (c < C) ? src[(size_t)(kt * 64 + k) * C + c] : 0.f;   // coalesced over c
    }
    __syncthreads();
    #pragma unroll
    for (int i = 0; i < 16; ++i) {
        const int cc = i * 4 + kr;
        const int c = c0 + cc;
        if (c < C) dst[(size_t)c * 256 + kt * 64 + cl] = t[cl][cc];      // coalesced over k
    }
}

// ---------------- fill helper (non-temporal streaming stores) ----------------
// NOTE: __builtin_nontemporal_store requires a scalar/ext-vector type;
// HIP's float4 struct is rejected -> use f32x4 (clang ext_vector).
__device__ __forceinline__ void fill_span(f32x4* __restrict__ dst, size_t n4,
                                          int fb, int nFB)
{
    const f32x4 v = {MASKED_VAL, MASKED_VAL, MASKED_VAL, MASKED_VAL};
    for (size_t i = (size_t)fb * 256 + threadIdx.x; i < n4; i += (size_t)nFB * 256)
        __builtin_nontemporal_store(v, dst + i);
}

__global__ __launch_bounds__(256)
void fill_kernel(f32x4* __restrict__ dst, size_t n4)
{
    fill_span(dst, n4, blockIdx.x, gridDim.x);
}

// ---------------- bf16x3 GEMM (global_load_lds, swizzled tiles) + fused fill ----
__device__ __forceinline__ void gload16(const ushort_t* g, ushort_t* l) {
    __builtin_amdgcn_global_load_lds(
        (const __attribute__((address_space(1))) u32*)g,
        (__attribute__((address_space(3))) u32*)l, 16, 0, 0);
}

__global__ __launch_bounds__(256)
void gemm_ts_fill(const ushort_t* __restrict__ Ahg, const ushort_t* __restrict__ Alg,
                  const ushort_t* __restrict__ Bhg, const ushort_t* __restrict__ Blg,
                  int K, float* __restrict__ Cbase, int chunkW, size_t chunkStride,
                  int nCT, int nGB, f32x4* __restrict__ fillDst, size_t fillN4)
{
    __shared__ ushort_t sAh[8192], sAl[8192], sBh[8192], sBl[8192];   // 64 KB

    if ((int)blockIdx.x >= nGB) {   // whole-block filler path (no divergence)
        fill_span(fillDst, fillN4, blockIdx.x - nGB, gridDim.x - nGB);
        return;
    }

    const int tid = threadIdx.x, w = tid >> 6, lane = tid & 63;
    const int wm = w >> 1, wn = w & 1;
    const int fr = lane & 15, kg = lane >> 4;
    const int nKT = K >> 6;
    const int rt = blockIdx.x / nCT, ct = blockIdx.x % nCT;
    const int col0 = ct * 128;
    const int chunk = col0 / chunkW;
    const int lc0 = col0 - chunk * chunkW;
    float* __restrict__ C = Cbase + (size_t)chunk * chunkStride;

    const int sbase = w * 2048;
    const int lgo = lane * 8;

    f32x4 acc[4][4] = {};

    for (int kt = 0; kt < nKT; ++kt) {
        const size_t at = ((size_t)rt * nKT + kt) * 8192;
        const size_t bt = ((size_t)ct * nKT + kt) * 8192;
        #pragma unroll
        for (int i = 0; i < 4; ++i) {
            const int co = sbase + i * 512;
            gload16(Ahg + at + co + lgo, &sAh[co]);
            gload16(Alg + at + co + lgo, &sAl[co]);
            gload16(Bhg + bt + co + lgo, &sBh[co]);
            gload16(Blg + bt + co + lgo, &sBl[co]);
        }
        __syncthreads();

        #pragma unroll
        for (int ks = 0; ks < 2; ++ks) {
            const int g = ks * 4 + kg;
            short8 a_h[4], a_l[4], b_h[4], b_l[4];
            #pragma unroll
            for (int i = 0; i < 4; ++i) {
                const int ra = wm * 64 + i * 16 + fr;
                const int pa = ra * 64 + ((g ^ (ra & 7)) << 3);
                a_h[i] = *(const short8*)&sAh[pa];
                a_l[i] = *(const short8*)&sAl[pa];
                const int rb = wn * 64 + i * 16 + fr;
                const int pb = rb * 64 + ((g ^ (rb & 7)) << 3);
                b_h[i] = *(const short8*)&sBh[pb];
                b_l[i] = *(const short8*)&sBl[pb];
            }
            #pragma unroll
            for (int mi = 0; mi < 4; ++mi) {
                #pragma unroll
                for (int ni = 0; ni < 4; ++ni) {
                    acc[mi][ni] = __builtin_amdgcn_mfma_f32_16x16x32_bf16(a_h[mi], b_h[ni], acc[mi][ni], 0, 0, 0);
                    acc[mi][ni] = __builtin_amdgcn_mfma_f32_16x16x32_bf16(a_h[mi], b_l[ni], acc[mi][ni], 0, 0, 0);
                    acc[mi][ni] = __builtin_amdgcn_mfma_f32_16x16x32_bf16(a_l[mi], b_h[ni], acc[mi][ni], 0, 0, 0);
                }
            }
        }
        __syncthreads();
    }

    const int crow = kg * 4;
    #pragma unroll
    for (int mi = 0; mi < 4; ++mi) {
        const int gr = rt * 128 + wm * 64 + mi * 16 + crow;
        #pragma unroll
        for (int ni = 0; ni < 4; ++ni) {
            const int gc = lc0 + wn * 64 + ni * 16 + fr;
            #pragma unroll
            for (int j = 0; j < 4; ++j)
                C[(size_t)(gr + j) * chunkW + gc] = acc[mi][ni][j];
        }
    }
}

// ---------------- chain: dots from transposed W_cls + argmax + compact ---------
template <int C, int P>
__device__ __forceinline__ int level_step_t(const float* __restrict__ WT,  // [C][256]
                                            const float* zrow,
                                            volatile float* lcomp,
                                            int p, int lane,
                                            float* __restrict__ rec /*6 fl*/)
{
    const int cnt = (C - p + P - 1) / P;   // 3..5
    if (lane < cnt) {
        const int c = p + lane * P;
        const float4* wv = (const float4*)(WT + (size_t)c * 256);
        float4 s0 = {0,0,0,0}, s1 = {0,0,0,0};
        #pragma unroll 8
        for (int q = 0; q < 64; q += 2) {
            const float4 w0 = wv[q], w1 = wv[q + 1];
            const float4 z0 = *(const float4*)&zrow[q * 4];
            const float4 z1 = *(const float4*)&zrow[q * 4 + 4];
            s0.x = fmaf(w0.x, z0.x, s0.x); s0.y = fmaf(w0.y, z0.y, s0.y);
            s0.z = fmaf(w0.z, z0.z, s0.z); s0.w = fmaf(w0.w, z0.w, s0.w);
            s1.x = fmaf(w1.x, z1.x, s1.x); s1.y = fmaf(w1.y, z1.y, s1.y);
            s1.z = fmaf(w1.z, z1.z, s1.z); s1.w = fmaf(w1.w, z1.w, s1.w);
        }
        lcomp[lane] = ((s0.x + s0.y) + (s0.z + s0.w)) + ((s1.x + s1.y) + (s1.z + s1.w));
    }
    asm volatile("s_waitcnt lgkmcnt(0)" ::: "memory");

    float best = lcomp[0];
    int bj = 0;
    #pragma unroll
    for (int j = 1; j < 5; ++j) {
        if (j < cnt) {
            float vj = lcomp[j];
            if (vj > best) { best = vj; bj = j; }
        }
    }

    if (lane == 0) rec[0] = __int_as_float(p);
    if (lane >= 1 && lane <= 5) rec[lane] = (lane - 1 < cnt) ? lcomp[lane - 1] : 0.f;

    return p + bj * P;
}

__global__ __launch_bounds__(256)
void chain_kernel(const float* __restrict__ z,
                  const float* __restrict__ Wp,   // [256][40] original
                  const float* __restrict__ ToT, const float* __restrict__ TfT,
                  const float* __restrict__ TgT, const float* __restrict__ TsT,
                  float* __restrict__ out, float* __restrict__ compact)
{
    __shared__ float zsh[4][256];
    __shared__ float lcomp[4][8];

    const int w    = threadIdx.x >> 6;
    const int lane = threadIdx.x & 63;
    const size_t b = (size_t)blockIdx.x * 4 + w;

    const float* zr = z + b * 256;
    *(float4*)&zsh[w][lane * 4] = *(const float4*)(zr + lane * 4);
    asm volatile("s_waitcnt lgkmcnt(0)" ::: "memory");
    const float* zrow = &zsh[w][0];

    float pv = MASKED_VAL;
    if (lane < 40) {
        float s0 = 0.f, s1 = 0.f, s2 = 0.f, s3 = 0.f;
        #pragma unroll 4
        for (int k = 0; k < 256; k += 4) {
            s0 = fmaf(zrow[k + 0], Wp[(k + 0) * 40 + lane], s0);
            s1 = fmaf(zrow[k + 1], Wp[(k + 1) * 40 + lane], s1);
            s2 = fmaf(zrow[k + 2], Wp[(k + 2) * 40 + lane], s2);
            s3 = fmaf(zrow[k + 3], Wp[(k + 3) * 40 + lane], s3);
        }
        pv = (s0 + s1) + (s2 + s3);
        out[OFF_LP + b * 40 + lane] = pv;
    }
    float v = pv;
    int idx = lane;
    #pragma unroll
    for (int off = 32; off; off >>= 1) {
        float ov = __shfl_xor(v, off);
        int   oi = __shfl_xor(idx, off);
        if (ov > v || (ov == v && oi < idx)) { v = ov; idx = oi; }
    }
    int p = idx;

    p = level_step_t<200, 40>    (ToT, zrow, lcomp[w], p, lane, compact + (0 * Bn + b) * 6);
    p = level_step_t<800, 200>   (TfT, zrow, lcomp[w], p, lane, compact + (1 * Bn + b) * 6);
    p = level_step_t<3000, 800>  (TgT, zrow, lcomp[w], p, lane, compact + (2 * Bn + b) * 6);
    (void)level_step_t<12000, 3000>(TsT, zrow, lcomp[w], p, lane, compact + (3 * Bn + b) * 6);
}

// ---------------- scatter valid logits over the sentinel fill ----------------
__global__ __launch_bounds__(256)
void scatter_kernel(const float* __restrict__ compact, float* __restrict__ out)
{
    const int t = blockIdx.x * 256 + threadIdx.x;
    if (t >= 4 * Bn) return;
    const int lvl = t >> 13, b = t & (Bn - 1);
    const int Cs[4] = {200, 800, 3000, 12000};
    const int Ps[4] = {40, 200, 800, 3000};
    const size_t OFFL[4] = {OFF_LO, OFF_LF, OFF_LG, OFF_LS};
    const float* rec = compact + ((size_t)lvl * Bn + b) * 6;
    const int p = __float_as_int(rec[0]);
    const int C = Cs[lvl], P = Ps[lvl];
    const int cnt = (C - p + P - 1) / P;
    float* dst = out + OFFL[lvl] + (size_t)b * C;
    for (int j = 0; j < cnt; ++j)
        dst[p + j * P] = rec[1 + j];
}

// ---------------- host launcher ----------------
extern "C" void kernel_launch(void* const* d_in, const int* in_sizes, int n_in,
                              void* d_out, int out_size, void* d_ws, size_t ws_size,
                              hipStream_t stream)
{
    const float* seq    = (const float*)d_in[0];
    const float* Wdna   = (const float*)d_in[1];
    const float* Wenc   = (const float*)d_in[2];
    const float* Wcls_p = (const float*)d_in[3];
    const float* Wdec_p = (const float*)d_in[4];
    const float* Wcls_o = (const float*)d_in[5];
    const float* Wdec_o = (const float*)d_in[6];
    const float* Wcls_f = (const float*)d_in[7];
    const float* Wdec_f = (const float*)d_in[8];
    const float* Wcls_g = (const float*)d_in[9];
    const float* Wdec_g = (const float*)d_in[10];
    const float* Wcls_s = (const float*)d_in[11];
    const float* Wdec_s = (const float*)d_in[12];
    const float* Wglob  = (const float*)d_in[13];
    (void)in_sizes; (void)n_in; (void)out_size; (void)ws_size;

    float* out = (float*)d_out;
    ushort_t* ws = (ushort_t*)d_ws;

    ushort_t* seqH = (ushort_t*)(out + S_SEQ_H);
    ushort_t* seqL = (ushort_t*)(out + S_SEQ_L);
    ushort_t* embH = (ushort_t*)(out + S_EMB_H);
    ushort_t* embL = (ushort_t*)(out + S_EMB_L);
    ushort_t* zH   = (ushort_t*)(out + S_Z_H);
    ushort_t* zL   = (ushort_t*)(out + S_Z_L);
    ushort_t* recH = (ushort_t*)(out + S_REC_H);
    ushort_t* recL = (ushort_t*)(out + S_REC_L);
    float* ToT = out + S_T_O;
    float* TfT = out + S_T_F;
    float* TgT = out + S_T_G;
    float* TsT = out + S_T_S;
    ushort_t* dnaH = ws + WS_DNA_H;
    ushort_t* dnaL = ws + WS_DNA_L;
    ushort_t* encH = ws + WS_ENC_H;
    ushort_t* encL = ws + WS_ENC_L;
    float* compact = (float*)ws + WS_COMPACT_FL;

    // --- preps ---
    prep_wtT<1024, 768><<<384, 256, 0, stream>>>(Wdna, dnaH, dnaL);
    prep_wtT<768, 256><<<96, 256, 0, stream>>>(Wenc, encH, encL);
    Ptr6 s6{{Wdec_p, Wdec_o, Wdec_f, Wdec_g, Wdec_s, Wglob}};
    prep_recT<<<576, 256, 0, stream>>>(s6, recH, recL);
    split_tiled<<<4096, 256, 0, stream>>>(seq, seqH, seqL, Bn, SEQ);
    transpose_cls<<<dim3(4, 4),   256, 0, stream>>>(Wcls_o, ToT, 200);
    transpose_cls<<<dim3(13, 4),  256, 0, stream>>>(Wcls_f, TfT, 800);
    transpose_cls<<<dim3(47, 4),  256, 0, stream>>>(Wcls_g, TgT, 3000);
    transpose_cls<<<dim3(188, 4), 256, 0, stream>>>(Wcls_s, TsT, 12000);

    // --- emb = seq @ Wdna  (+ fused fill-A: non-scratch logit tail, 436MB) ---
    gemm_ts_fill<<<384 + 1664, 256, 0, stream>>>(
        seqH, seqL, dnaH, dnaL, SEQ, out + OFF_EMB, EMB, 0,
        6, 384, (f32x4*)(out + SCR_END), FILLA_N4);
    split_tiled<<<3072, 256, 0, stream>>>(out + OFF_EMB, embH, embL, Bn, EMB);

    // --- z = emb @ Wenc  (+ fused fill of dead seqH/L, 33.5MB) ---
    gemm_ts_fill<<<128 + 896, 256, 0, stream>>>(
        embH, embL, encH, encL, EMB, out + OFF_Z, LAT, 0,
        2, 128, (f32x4*)(out + SCR), FILLZ_N4);
    split_tiled<<<1024, 256, 0, stream>>>(out + OFF_Z, zH, zL, Bn, LAT);

    // --- fused recons + global: z @ [Wdec_p|...|Wglob]  (+ fill dead embH/L, 25MB) ---
    gemm_ts_fill<<<2304 + 768, 256, 0, stream>>>(
        zH, zL, recH, recL, LAT, out + OFF_RP, EMB, (size_t)Bn * EMB,
        36, 2304, (f32x4*)(out + S_EMB_H), FILLR_N4);

    // --- chain compute (reads cls_T scratch; must precede fill-B) ---
    chain_kernel<<<dim3(Bn / 4), 256, 0, stream>>>(out + OFF_Z, Wcls_p, ToT, TfT,
                                                   TgT, TsT, out, compact);

    // --- fill-B: remaining scratch span (z/rec/cls_T, 29.5MB), then scatter ---
    fill_kernel<<<512, 256, 0, stream>>>((f32x4*)(out + S_Z_H), FILLB_N4);
    scatter_kernel<<<(4 * Bn + 255) / 256, 256, 0, stream>>>(compact, out);
}

// Round 8
// 308.572 us; speedup vs baseline: 1.6910x; 1.3301x over previous
//
#include <hip/hip_runtime.h>
#include <hip/hip_bf16.h>

typedef __attribute__((ext_vector_type(8))) short short8;
typedef __attribute__((ext_vector_type(4))) float f32x4;
typedef unsigned short ushort_t;
typedef unsigned int u32;

// ---------------- problem constants ----------------
static constexpr int Bn  = 8192;
static constexpr int SEQ = 1024;
static constexpr int EMB = 768;
static constexpr int LAT = 256;

// output offsets (floats): (z, Lp, Lo, Lf, Lg, Ls, Rp, Ro, Rf, Rg, Rs, glob, emb)
static constexpr size_t OFF_Z   = 0;
static constexpr size_t OFF_LP  = 2097152;
static constexpr size_t OFF_LO  = 2424832;
static constexpr size_t OFF_LF  = 4063232;
static constexpr size_t OFF_LG  = 10616832;
static constexpr size_t OFF_LS  = 35192832;
static constexpr size_t OFF_RP  = 133496832;  // Rp..Rs,glob contiguous, stride 8192*768
static constexpr size_t OFF_EMB = 171245568;

// Scratch inside the masked-logit region [OFF_LO, OFF_RP).
static constexpr size_t SCR      = OFF_LO;
static constexpr size_t S_SEQ_H  = SCR + 0;         // 8192x1024 bf16 tiles
static constexpr size_t S_SEQ_L  = SCR + 4194304;
static constexpr size_t S_EMB_H  = SCR + 8388608;   // 8192x768
static constexpr size_t S_EMB_L  = SCR + 11534336;
static constexpr size_t S_Z_H    = SCR + 14680064;  // 8192x256
static constexpr size_t S_Z_L    = SCR + 15728640;
static constexpr size_t S_REC_H  = SCR + 16777216;  // 4608x256
static constexpr size_t S_REC_L  = SCR + 17367040;  // end 17956864
static constexpr size_t S_CLS_T  = SCR + 17956864;  // transposed W_cls (f32)
static constexpr size_t S_T_O    = S_CLS_T + 0;        // 200*256
static constexpr size_t S_T_F    = S_CLS_T + 51200;    // 800*256
static constexpr size_t S_T_G    = S_CLS_T + 256000;   // 3000*256
static constexpr size_t S_T_S    = S_CLS_T + 1024000;  // 12000*256 -> end SCR+22052864

// Tail = non-scratch masked-logit space: NO reader ever -> fillable in any window.
// Distributed over windows w/ spare write BW (f4 units within the tail):
static constexpr size_t SCR_END   = SCR + 22052864;
static constexpr size_t TAIL_N4   = (OFF_RP - SCR_END) / 4;  // 27254784 f4 (436MB)
static constexpr size_t T_SEQ0 = 0,        T_SEQ1 = 3276800;   // 50MB  @ seq split
static constexpr size_t T_EMB0 = 3276800,  T_EMB1 = 16384000;  // 200MB @ emb GEMM
static constexpr size_t T_Z0   = 16384000, T_Z1   = 18743296;  // 36MB  @ z GEMM
static constexpr size_t T_R0   = 18743296, T_R1   = 27254784;  // 130MB @ recon GEMM
static constexpr size_t FILLZ_N4  = 8388608 / 4;               // seqH/L (dead after emb)
static constexpr size_t FILLR_N4  = (14680064 - 8388608) / 4;  // embH/L (dead after z)
static constexpr size_t FILLB_N4  = (22052864 - 14680064) / 4; // z/rec/cls_T (after chain)

// d_ws layout (ushort units); <= 4.72 MB used (8.65 MB proven safe in R2/R3).
static constexpr size_t WS_DNA_H = 0;        // 768x1024 tiles
static constexpr size_t WS_DNA_L = 786432;
static constexpr size_t WS_ENC_H = 1572864;  // 256x768 tiles
static constexpr size_t WS_ENC_L = 1769472;
static constexpr size_t WS_COMPACT_FL = 983040; // float offset: 4 x 8192 x 6

#define MASKED_VAL (-1.0e30f)

// ---------------- bf16 split helpers (RNE) ----------------
__device__ __forceinline__ ushort_t bfbits(float f) {
    return __builtin_bit_cast(ushort_t, __float2bfloat16(f));
}
__device__ __forceinline__ float bf2f(ushort_t h) {
    return __builtin_bit_cast(float, ((unsigned)h) << 16);
}
__device__ __forceinline__ void split2(float f, ushort_t& h, ushort_t& l) {
    h = bfbits(f);
    l = bfbits(f - bf2f(h));
}

// Tiled-swizzled operand layout: tiles of 128 rows x 64 k (bf16), tile-major
// [rowTile][kTile]; within tile, 16B granule g of row r sits at granule (g^(r&7)).
__device__ __forceinline__ size_t tile_pos(int rt, int nKT, int kt, int r, int g) {
    return ((size_t)rt * nKT + kt) * 8192 + (size_t)r * 64 + ((g ^ (r & 7)) << 3);
}

// ---------------- fill helper (non-temporal streaming stores) ----------------
__device__ __forceinline__ void fill_span(f32x4* __restrict__ dst, size_t n4,
                                          int fb, int nFB)
{
    const f32x4 v = {MASKED_VAL, MASKED_VAL, MASKED_VAL, MASKED_VAL};
    for (size_t i = (size_t)fb * 256 + threadIdx.x; i < n4; i += (size_t)nFB * 256)
        __builtin_nontemporal_store(v, dst + i);
}

__global__ __launch_bounds__(256)
void fill_kernel(f32x4* __restrict__ dst, size_t n4)
{
    fill_span(dst, n4, blockIdx.x, gridDim.x);
}

// ---------------- merged weight prep (dna + enc + rec) ----------------
__device__ __forceinline__ void prep_wtT_body(const float* __restrict__ src,
                                              ushort_t* __restrict__ dh,
                                              ushort_t* __restrict__ dl,
                                              int K, int N, int bx, int nb)
{
    const int gpr = K >> 3, nKT = K >> 6;
    const int nG = N * gpr;
    for (int gi = bx * 256 + threadIdx.x; gi < nG; gi += nb * 256) {
        const int n = gi / gpr, gk = gi - n * gpr;
        short8 hh, ll;
        #pragma unroll
        for (int j = 0; j < 8; ++j) {
            ushort_t hv, lv;
            split2(src[(size_t)(gk * 8 + j) * N + n], hv, lv);
            hh[j] = (short)hv; ll[j] = (short)lv;
        }
        const size_t base = tile_pos(n >> 7, nKT, gk >> 3, n & 127, gk & 7);
        *(short8*)(dh + base) = hh;
        *(short8*)(dl + base) = ll;
    }
}

struct Ptr6 { const float* p[6]; };

__device__ __forceinline__ void prep_rec_body(Ptr6 s, ushort_t* __restrict__ dh,
                                              ushort_t* __restrict__ dl, int bx, int nb)
{
    constexpr int gpr = 32, nKT = 4;   // K = 256
    const int nG = 4608 * gpr;
    for (int gi = bx * 256 + threadIdx.x; gi < nG; gi += nb * 256) {
        const int np = gi / gpr, gk = gi - np * gpr;
        const int m = np / 768, nn = np - m * 768;
        const float* sm = s.p[m];
        short8 hh, ll;
        #pragma unroll
        for (int j = 0; j < 8; ++j) {
            ushort_t hv, lv;
            split2(sm[(size_t)(gk * 8 + j) * 768 + nn], hv, lv);
            hh[j] = (short)hv; ll[j] = (short)lv;
        }
        const size_t base = tile_pos(np >> 7, nKT, gk >> 3, np & 127, gk & 7);
        *(short8*)(dh + base) = hh;
        *(short8*)(dl + base) = ll;
    }
}

__global__ __launch_bounds__(256)
void prep_all(const float* __restrict__ Wdna, ushort_t* dnaH, ushort_t* dnaL,
              const float* __restrict__ Wenc, ushort_t* encH, ushort_t* encL,
              Ptr6 s6, ushort_t* recH, ushort_t* recL)
{
    const int bx = blockIdx.x;
    if (bx < 384)       prep_wtT_body(Wdna, dnaH, dnaL, 1024, 768, bx, 384);
    else if (bx < 480)  prep_wtT_body(Wenc, encH, encL, 768, 256, bx - 384, 96);
    else                prep_rec_body(s6, recH, recL, bx - 480, 576);
}

// ---------------- merged LDS-tiled transposes: W_cls [256][C] -> [C][256] -----
__global__ __launch_bounds__(256)
void transpose_all(const float* __restrict__ Wo, const float* __restrict__ Wf,
                   const float* __restrict__ Wg, const float* __restrict__ Ws,
                   float* To, float* Tf, float* Tg, float* Ts)
{
    __shared__ float t[64][65];
    int bx = blockIdx.x;
    const float* src; float* dst; int C; int cb;
    if (bx < 16)       { src = Wo; dst = To; C = 200;   cb = bx; }
    else if (bx < 68)  { src = Wf; dst = Tf; C = 800;   cb = bx - 16; }
    else if (bx < 256) { src = Wg; dst = Tg; C = 3000;  cb = bx - 68; }
    else               { src = Ws; dst = Ts; C = 12000; cb = bx - 256; }
    const int ct = cb >> 2, kt = cb & 3;
    const int c0 = ct * 64;
    const int tid = threadIdx.x;
    const int cl = tid & 63, kr = tid >> 6;
    #pragma unroll
    for (int i = 0; i < 16; ++i) {
        const int k = i * 4 + kr;
        const int c = c0 + cl;
        t[k][cl] = (c < C) ? src[(size_t)(kt * 64 + k) * C + c] : 0.f;
    }
    __syncthreads();
    #pragma unroll
    for (int i = 0; i < 16; ++i) {
        const int cc = i * 4 + kr;
        const int c = c0 + cc;
        if (c < C) dst[(size_t)c * 256 + kt * 64 + cl] = t[cl][cc];
    }
}

// ---------------- seq split (+ fused tail fill) ----------------
__global__ __launch_bounds__(256)
void split_tiled_fill(const float* __restrict__ src, ushort_t* __restrict__ dh,
                      ushort_t* __restrict__ dl, int M, int K,
                      int nGB, f32x4* __restrict__ f1, size_t n1)
{
    if ((int)blockIdx.x >= nGB) {
        fill_span(f1, n1, blockIdx.x - nGB, gridDim.x - nGB);
        return;
    }
    const int gpr = K >> 3, nKT = K >> 6;
    const int nG = M * gpr;
    for (int gi = blockIdx.x * 256 + threadIdx.x; gi < nG; gi += nGB * 256) {
        const int row = gi / gpr, gk = gi - row * gpr;
        const float* s = src + (size_t)row * K + gk * 8;
        const float4 a = *(const float4*)s;
        const float4 b = *(const float4*)(s + 4);
        const float f[8] = {a.x, a.y, a.z, a.w, b.x, b.y, b.z, b.w};
        short8 hh, ll;
        #pragma unroll
        for (int j = 0; j < 8; ++j) {
            ushort_t hv, lv;
            split2(f[j], hv, lv);
            hh[j] = (short)hv; ll[j] = (short)lv;
        }
        const size_t base = tile_pos(row >> 7, nKT, gk >> 3, row & 127, gk & 7);
        *(short8*)(dh + base) = hh;
        *(short8*)(dl + base) = ll;
    }
}

// plain split (emb, z)
__global__ __launch_bounds__(256)
void split_tiled(const float* __restrict__ src, ushort_t* __restrict__ dh,
                 ushort_t* __restrict__ dl, int M, int K)
{
    const int gpr = K >> 3, nKT = K >> 6;
    const int nG = M * gpr;
    for (int gi = blockIdx.x * 256 + threadIdx.x; gi < nG; gi += gridDim.x * 256) {
        const int row = gi / gpr, gk = gi - row * gpr;
        const float* s = src + (size_t)row * K + gk * 8;
        const float4 a = *(const float4*)s;
        const float4 b = *(const float4*)(s + 4);
        const float f[8] = {a.x, a.y, a.z, a.w, b.x, b.y, b.z, b.w};
        short8 hh, ll;
        #pragma unroll
        for (int j = 0; j < 8; ++j) {
            ushort_t hv, lv;
            split2(f[j], hv, lv);
            hh[j] = (short)hv; ll[j] = (short)lv;
        }
        const size_t base = tile_pos(row >> 7, nKT, gk >> 3, row & 127, gk & 7);
        *(short8*)(dh + base) = hh;
        *(short8*)(dl + base) = ll;
    }
}

// ---------------- bf16x3 GEMM (global_load_lds, swizzled tiles) + 2-span fill ----
__device__ __forceinline__ void gload16(const ushort_t* g, ushort_t* l) {
    __builtin_amdgcn_global_load_lds(
        (const __attribute__((address_space(1))) u32*)g,
        (__attribute__((address_space(3))) u32*)l, 16, 0, 0);
}

__global__ __launch_bounds__(256)
void gemm_ts_fill(const ushort_t* __restrict__ Ahg, const ushort_t* __restrict__ Alg,
                  const ushort_t* __restrict__ Bhg, const ushort_t* __restrict__ Blg,
                  int K, float* __restrict__ Cbase, int chunkW, size_t chunkStride,
                  int nCT, int nGB,
                  f32x4* __restrict__ f1, size_t n1,
                  f32x4* __restrict__ f2, size_t n2)
{
    __shared__ ushort_t sAh[8192], sAl[8192], sBh[8192], sBl[8192];   // 64 KB

    if ((int)blockIdx.x >= nGB) {   // whole-block filler path (no divergence)
        const int fb = blockIdx.x - nGB, nFB = gridDim.x - nGB;
        fill_span(f1, n1, fb, nFB);
        if (n2) fill_span(f2, n2, fb, nFB);
        return;
    }

    const int tid = threadIdx.x, w = tid >> 6, lane = tid & 63;
    const int wm = w >> 1, wn = w & 1;
    const int fr = lane & 15, kg = lane >> 4;
    const int nKT = K >> 6;
    const int rt = blockIdx.x / nCT, ct = blockIdx.x % nCT;
    const int col0 = ct * 128;
    const int chunk = col0 / chunkW;
    const int lc0 = col0 - chunk * chunkW;
    float* __restrict__ C = Cbase + (size_t)chunk * chunkStride;

    const int sbase = w * 2048;
    const int lgo = lane * 8;

    f32x4 acc[4][4] = {};

    for (int kt = 0; kt < nKT; ++kt) {
        const size_t at = ((size_t)rt * nKT + kt) * 8192;
        const size_t bt = ((size_t)ct * nKT + kt) * 8192;
        #pragma unroll
        for (int i = 0; i < 4; ++i) {
            const int co = sbase + i * 512;
            gload16(Ahg + at + co + lgo, &sAh[co]);
            gload16(Alg + at + co + lgo, &sAl[co]);
            gload16(Bhg + bt + co + lgo, &sBh[co]);
            gload16(Blg + bt + co + lgo, &sBl[co]);
        }
        __syncthreads();

        #pragma unroll
        for (int ks = 0; ks < 2; ++ks) {
            const int g = ks * 4 + kg;
            short8 a_h[4], a_l[4], b_h[4], b_l[4];
            #pragma unroll
            for (int i = 0; i < 4; ++i) {
                const int ra = wm * 64 + i * 16 + fr;
                const int pa = ra * 64 + ((g ^ (ra & 7)) << 3);
                a_h[i] = *(const short8*)&sAh[pa];
                a_l[i] = *(const short8*)&sAl[pa];
                const int rb = wn * 64 + i * 16 + fr;
                const int pb = rb * 64 + ((g ^ (rb & 7)) << 3);
                b_h[i] = *(const short8*)&sBh[pb];
                b_l[i] = *(const short8*)&sBl[pb];
            }
            #pragma unroll
            for (int mi = 0; mi < 4; ++mi) {
                #pragma unroll
                for (int ni = 0; ni < 4; ++ni) {
                    acc[mi][ni] = __builtin_amdgcn_mfma_f32_16x16x32_bf16(a_h[mi], b_h[ni], acc[mi][ni], 0, 0, 0);
                    acc[mi][ni] = __builtin_amdgcn_mfma_f32_16x16x32_bf16(a_h[mi], b_l[ni], acc[mi][ni], 0, 0, 0);
                    acc[mi][ni] = __builtin_amdgcn_mfma_f32_16x16x32_bf16(a_l[mi], b_h[ni], acc[mi][ni], 0, 0, 0);
                }
            }
        }
        __syncthreads();
    }

    const int crow = kg * 4;
    #pragma unroll
    for (int mi = 0; mi < 4; ++mi) {
        const int gr = rt * 128 + wm * 64 + mi * 16 + crow;
        #pragma unroll
        for (int ni = 0; ni < 4; ++ni) {
            const int gc = lc0 + wn * 64 + ni * 16 + fr;
            #pragma unroll
            for (int j = 0; j < 4; ++j)
                C[(size_t)(gr + j) * chunkW + gc] = acc[mi][ni][j];
        }
    }
}

// ---------------- chain: wave-parallel level dots + argmax + compact ----------
template <int C, int P>
__device__ __forceinline__ int level_w(const float* __restrict__ WT,  // [C][256]
                                       float4 zr, int p, int lane,
                                       float* __restrict__ rec /*6 fl*/)
{
    const int cnt = (C - p + P - 1) / P;   // 3..5, wave-uniform
    float sv[5];
    #pragma unroll
    for (int j = 0; j < 5; ++j) {
        float s = 0.f;
        if (j < cnt) {   // uniform branch: coalesced 1KB row load, all 64 lanes
            const float4 wv = *(const float4*)(WT + (size_t)(p + j * P) * 256 + lane * 4);
            s = fmaf(wv.x, zr.x, fmaf(wv.y, zr.y, fmaf(wv.z, zr.z, wv.w * zr.w)));
        }
        sv[j] = s;
    }
    #pragma unroll
    for (int j = 0; j < 5; ++j) {
        if (j < cnt) {
            #pragma unroll
            for (int off = 32; off; off >>= 1) sv[j] += __shfl_xor(sv[j], off);
        }
    }
    float best = sv[0];
    int bj = 0;
    #pragma unroll
    for (int j = 1; j < 5; ++j)
        if (j < cnt && sv[j] > best) { best = sv[j]; bj = j; }   // strict > = first-idx ties

    if (lane == 0) {   // static indices only (rule #20)
        rec[0] = __int_as_float(p);
        rec[1] = sv[0];
        rec[2] = (1 < cnt) ? sv[1] : 0.f;
        rec[3] = (2 < cnt) ? sv[2] : 0.f;
        rec[4] = (3 < cnt) ? sv[3] : 0.f;
        rec[5] = (4 < cnt) ? sv[4] : 0.f;
    }
    return p + bj * P;
}

__global__ __launch_bounds__(256)
void chain_kernel(const float* __restrict__ z,
                  const float* __restrict__ Wp,   // [256][40] original
                  const float* __restrict__ ToT, const float* __restrict__ TfT,
                  const float* __restrict__ TgT, const float* __restrict__ TsT,
                  float* __restrict__ out, float* __restrict__ compact)
{
    __shared__ float zsh[4][256];

    const int w    = threadIdx.x >> 6;
    const int lane = threadIdx.x & 63;
    const size_t b = (size_t)blockIdx.x * 4 + w;

    const float4 zr4 = *(const float4*)(z + b * 256 + lane * 4);
    *(float4*)&zsh[w][lane * 4] = zr4;
    asm volatile("s_waitcnt lgkmcnt(0)" ::: "memory");
    const float* zrow = &zsh[w][0];

    // phylum: 40 dense logits (unmasked), lane = column
    float pv = MASKED_VAL;
    if (lane < 40) {
        float s0 = 0.f, s1 = 0.f, s2 = 0.f, s3 = 0.f;
        #pragma unroll 4
        for (int k = 0; k < 256; k += 4) {
            s0 = fmaf(zrow[k + 0], Wp[(k + 0) * 40 + lane], s0);
            s1 = fmaf(zrow[k + 1], Wp[(k + 1) * 40 + lane], s1);
            s2 = fmaf(zrow[k + 2], Wp[(k + 2) * 40 + lane], s2);
            s3 = fmaf(zrow[k + 3], Wp[(k + 3) * 40 + lane], s3);
        }
        pv = (s0 + s1) + (s2 + s3);
        out[OFF_LP + b * 40 + lane] = pv;
    }
    float v = pv;
    int idx = lane;
    #pragma unroll
    for (int off = 32; off; off >>= 1) {
        float ov = __shfl_xor(v, off);
        int   oi = __shfl_xor(idx, off);
        if (ov > v || (ov == v && oi < idx)) { v = ov; idx = oi; }
    }
    int p = idx;

    p = level_w<200, 40>    (ToT, zr4, p, lane, compact + (0 * Bn + b) * 6);
    p = level_w<800, 200>   (TfT, zr4, p, lane, compact + (1 * Bn + b) * 6);
    p = level_w<3000, 800>  (TgT, zr4, p, lane, compact + (2 * Bn + b) * 6);
    (void)level_w<12000, 3000>(TsT, zr4, p, lane, compact + (3 * Bn + b) * 6);
}

// ---------------- scatter valid logits over the sentinel fill ----------------
__global__ __launch_bounds__(256)
void scatter_kernel(const float* __restrict__ compact, float* __restrict__ out)
{
    const int t = blockIdx.x * 256 + threadIdx.x;
    if (t >= 4 * Bn) return;
    const int lvl = t >> 13, b = t & (Bn - 1);
    const int Cs[4] = {200, 800, 3000, 12000};
    const int Ps[4] = {40, 200, 800, 3000};
    const size_t OFFL[4] = {OFF_LO, OFF_LF, OFF_LG, OFF_LS};
    const float* rec = compact + ((size_t)lvl * Bn + b) * 6;
    const int p = __float_as_int(rec[0]);
    const int C = Cs[lvl], P = Ps[lvl];
    const int cnt = (C - p + P - 1) / P;
    float* dst = out + OFFL[lvl] + (size_t)b * C;
    for (int j = 0; j < cnt; ++j)
        dst[p + j * P] = rec[1 + j];
}

// ---------------- host launcher ----------------
extern "C" void kernel_launch(void* const* d_in, const int* in_sizes, int n_in,
                              void* d_out, int out_size, void* d_ws, size_t ws_size,
                              hipStream_t stream)
{
    const float* seq    = (const float*)d_in[0];
    const float* Wdna   = (const float*)d_in[1];
    const float* Wenc   = (const float*)d_in[2];
    const float* Wcls_p = (const float*)d_in[3];
    const float* Wdec_p = (const float*)d_in[4];
    const float* Wcls_o = (const float*)d_in[5];
    const float* Wdec_o = (const float*)d_in[6];
    const float* Wcls_f = (const float*)d_in[7];
    const float* Wdec_f = (const float*)d_in[8];
    const float* Wcls_g = (const float*)d_in[9];
    const float* Wdec_g = (const float*)d_in[10];
    const float* Wcls_s = (const float*)d_in[11];
    const float* Wdec_s = (const float*)d_in[12];
    const float* Wglob  = (const float*)d_in[13];
    (void)in_sizes; (void)n_in; (void)out_size; (void)ws_size;

    float* out = (float*)d_out;
    ushort_t* ws = (ushort_t*)d_ws;

    ushort_t* seqH = (ushort_t*)(out + S_SEQ_H);
    ushort_t* seqL = (ushort_t*)(out + S_SEQ_L);
    ushort_t* embH = (ushort_t*)(out + S_EMB_H);
    ushort_t* embL = (ushort_t*)(out + S_EMB_L);
    ushort_t* zH   = (ushort_t*)(out + S_Z_H);
    ushort_t* zL   = (ushort_t*)(out + S_Z_L);
    ushort_t* recH = (ushort_t*)(out + S_REC_H);
    ushort_t* recL = (ushort_t*)(out + S_REC_L);
    float* ToT = out + S_T_O;
    float* TfT = out + S_T_F;
    float* TgT = out + S_T_G;
    float* TsT = out + S_T_S;
    ushort_t* dnaH = ws + WS_DNA_H;
    ushort_t* dnaL = ws + WS_DNA_L;
    ushort_t* encH = ws + WS_ENC_H;
    ushort_t* encL = ws + WS_ENC_L;
    float* compact = (float*)ws + WS_COMPACT_FL;
    f32x4* tail = (f32x4*)(out + SCR_END);

    // --- merged preps (dna 384 | enc 96 | rec 576 blocks) ---
    Ptr6 s6{{Wdec_p, Wdec_o, Wdec_f, Wdec_g, Wdec_s, Wglob}};
    prep_all<<<1056, 256, 0, stream>>>(Wdna, dnaH, dnaL, Wenc, encH, encL, s6, recH, recL);
    // --- merged transposes (o 16 | f 52 | g 188 | s 752 blocks) ---
    transpose_all<<<1008, 256, 0, stream>>>(Wcls_o, Wcls_f, Wcls_g, Wcls_s,
                                            ToT, TfT, TgT, TsT);
    // --- seq split + 50MB tail fill ---
    split_tiled_fill<<<4096 + 448, 256, 0, stream>>>(seq, seqH, seqL, Bn, SEQ,
                                                     4096, tail + T_SEQ0, T_SEQ1 - T_SEQ0);

    // --- emb = seq @ Wdna  (+ 200MB tail fill) ---
    gemm_ts_fill<<<384 + 1664, 256, 0, stream>>>(
        seqH, seqL, dnaH, dnaL, SEQ, out + OFF_EMB, EMB, 0, 6, 384,
        tail + T_EMB0, T_EMB1 - T_EMB0, nullptr, 0);
    split_tiled<<<3072, 256, 0, stream>>>(out + OFF_EMB, embH, embL, Bn, EMB);

    // --- z = emb @ Wenc  (+ fill dead seqH/L 33.5MB + 36MB tail) ---
    gemm_ts_fill<<<128 + 896, 256, 0, stream>>>(
        embH, embL, encH, encL, EMB, out + OFF_Z, LAT, 0, 2, 128,
        (f32x4*)(out + SCR), FILLZ_N4, tail + T_Z0, T_Z1 - T_Z0);
    split_tiled<<<1024, 256, 0, stream>>>(out + OFF_Z, zH, zL, Bn, LAT);

    // --- fused recons + global  (+ fill dead embH/L 25MB + 130MB tail) ---
    gemm_ts_fill<<<2304 + 768, 256, 0, stream>>>(
        zH, zL, recH, recL, LAT, out + OFF_RP, EMB, (size_t)Bn * EMB, 36, 2304,
        (f32x4*)(out + S_EMB_H), FILLR_N4, tail + T_R0, T_R1 - T_R0);

    // --- chain compute (reads cls_T scratch; must precede fill-B) ---
    chain_kernel<<<dim3(Bn / 4), 256, 0, stream>>>(out + OFF_Z, Wcls_p, ToT, TfT,
                                                   TgT, TsT, out, compact);

    // --- fill-B: z/rec/cls_T scratch (29.5MB), then scatter ---
    fill_kernel<<<512, 256, 0, stream>>>((f32x4*)(out + S_Z_H), FILLB_N4);
    scatter_kernel<<<(4 * Bn + 255) / 256, 256, 0, stream>>>(compact, out);
}